// Round 17
// baseline (312.909 us; speedup 1.0000x reference)
//
#include <hip/hip_runtime.h>
#include <hip/hip_bf16.h>

#define N_NODES 100000
#define IN_DIM 256
#define OUT_DIM 64
#define INV_KEEP 1.1111111111111112f  // 1/0.9

// bucket = 256 consecutive rows; record = (val, col<<8 | row&255)
#define BROWS 256
#define NBUCKET ((N_NODES + BROWS - 1) / BROWS)   // 391
#define PBLK 256     // chunking blocks per array for hist/place
#define A_CAP 9728   // max records/bucket (mean 8184, sigma 90 -> +17 sigma)
#define X_CAP 5120   // mean ~3680, sigma 60 -> +24 sigma; 5120*8B = 40KB LDS

__device__ __forceinline__ int   ldnt (const int* p)   { return __builtin_nontemporal_load(p); }
__device__ __forceinline__ float ldntf(const float* p) { return __builtin_nontemporal_load(p); }

// ============ pass 1: per-(block,bucket) counts, no global atomics ============
__global__ __launch_bounds__(256) void hist_count_kernel(
    const int* __restrict__ xr, const int* __restrict__ keep,
    const int* __restrict__ ar,
    int* __restrict__ cnt_blk_x, int* __restrict__ cnt_blk_a,
    int x_nnz, int a_nnz)
{
    __shared__ int cnt[NBUCKET];
    const bool isA = blockIdx.x >= PBLK;
    const int ib = isA ? (int)blockIdx.x - PBLK : (int)blockIdx.x;
    const int nnz = isA ? a_nnz : x_nnz;
    const int chunk = (nnz + PBLK - 1) / PBLK;
    const int lo = ib * chunk, hi = min(lo + chunk, nnz);

    for (int k = threadIdx.x; k < NBUCKET; k += 256) cnt[k] = 0;
    __syncthreads();
    if (isA) {
        for (int e = lo + (int)threadIdx.x; e < hi; e += 256)
            atomicAdd(&cnt[ldnt(ar + e) >> 8], 1);
    } else {
        for (int e = lo + (int)threadIdx.x; e < hi; e += 256)
            if (ldnt(keep + e) != 0) atomicAdd(&cnt[ldnt(xr + e) >> 8], 1);
    }
    __syncthreads();
    int* dst = (isA ? cnt_blk_a : cnt_blk_x) + (size_t)ib * NBUCKET;
    for (int k = threadIdx.x; k < NBUCKET; k += 256) dst[k] = cnt[k];
}

// ============ pass 2a: per-bucket exclusive scan over PBLK block counts ============
__global__ __launch_bounds__(256) void colscan_kernel(
    int* __restrict__ cnt_blk_x, int* __restrict__ cnt_blk_a,
    int* __restrict__ btot_x, int* __restrict__ btot_a)
{
    const bool isA = blockIdx.x >= NBUCKET;
    const int k = isA ? (int)blockIdx.x - NBUCKET : (int)blockIdx.x;
    int* cb = isA ? cnt_blk_a : cnt_blk_x;
    __shared__ int sc[PBLK];
    const int t = threadIdx.x;                 // 256 == PBLK
    int v = cb[(size_t)t * NBUCKET + k];
    sc[t] = v;
    __syncthreads();
    for (int off = 1; off < PBLK; off <<= 1) {
        int u = (t >= off) ? sc[t - off] : 0;
        __syncthreads();
        sc[t] += u;
        __syncthreads();
    }
    cb[(size_t)t * NBUCKET + k] = sc[t] - v;   // exclusive within bucket
    if (t == PBLK - 1) (isA ? btot_a : btot_x)[k] = sc[t];
}

// ============ pass 2b: scan bucket totals -> bstart ============
__global__ __launch_bounds__(512) void bucket_scan_kernel(
    const int* __restrict__ btot_x, const int* __restrict__ btot_a,
    int* __restrict__ bstart_x, int* __restrict__ bstart_a)
{
    const int* c = blockIdx.x ? btot_a : btot_x;
    int* bs      = blockIdx.x ? bstart_a : bstart_x;
    __shared__ int sc[512];
    const int t = threadIdx.x;
    sc[t] = (t < NBUCKET) ? c[t] : 0;
    __syncthreads();
    for (int off = 1; off < 512; off <<= 1) {
        int u = (t >= off) ? sc[t - off] : 0;
        __syncthreads();
        sc[t] += u;
        __syncthreads();
    }
    if (t < NBUCKET) bs[t] = (t > 0) ? sc[t - 1] : 0;
    if (t == NBUCKET - 1) bs[NBUCKET] = sc[t];
}

// ============ pass 3: single-pass placement into exact block-private ranges ============
__global__ __launch_bounds__(256) void partition_place_kernel(
    const float* __restrict__ xv, const int* __restrict__ xr,
    const int* __restrict__ xc, const int* __restrict__ keep,
    const float* __restrict__ av, const int* __restrict__ ar,
    const int* __restrict__ ac,
    const int* __restrict__ cnt_blk_x, const int* __restrict__ cnt_blk_a,
    const int* __restrict__ bstart_x, const int* __restrict__ bstart_a,
    float2* __restrict__ xs, float2* __restrict__ as, int x_nnz, int a_nnz)
{
    __shared__ int off_l[NBUCKET];
    const bool isA = blockIdx.x >= PBLK;
    const int ib = isA ? (int)blockIdx.x - PBLK : (int)blockIdx.x;
    const int nnz = isA ? a_nnz : x_nnz;
    const int chunk = (nnz + PBLK - 1) / PBLK;
    const int lo = ib * chunk, hi = min(lo + chunk, nnz);
    const int* cb = (isA ? cnt_blk_a : cnt_blk_x) + (size_t)ib * NBUCKET;
    const int* bs = isA ? bstart_a : bstart_x;
    float2* out   = isA ? as : xs;

    for (int k = threadIdx.x; k < NBUCKET; k += 256) off_l[k] = bs[k] + cb[k];
    __syncthreads();
    if (isA) {
        for (int e = lo + (int)threadIdx.x; e < hi; e += 256) {
            int r = ldnt(ar + e), c = ldnt(ac + e);
            float v = ldntf(av + e);
            int pos = atomicAdd(&off_l[r >> 8], 1);
            out[pos] = make_float2(v, __uint_as_float(((unsigned)c << 8) | (unsigned)(r & (BROWS - 1))));
        }
    } else {
        for (int e = lo + (int)threadIdx.x; e < hi; e += 256) {
            if (ldnt(keep + e) == 0) continue;
            int r = ldnt(xr + e), c = ldnt(xc + e);
            float v = ldntf(xv + e) * INV_KEEP;
            int pos = atomicAdd(&off_l[r >> 8], 1);
            out[pos] = make_float2(v, __uint_as_float(((unsigned)c << 8) | (unsigned)(r & (BROWS - 1))));
        }
    }
}

// ============ fused reorder_x + spmm1: group records in LDS, compute h ============
// Block per bucket: (1) LDS-count rows, (2) scan, (3) re-read records placing
// row-grouped in LDS, (4) wave w register-computes rows w*64..w*64+63 from LDS
// records (wave-uniform ds_read broadcast) + L2-resident W gathers.
// Eliminates reorder_x's global writeback + spmm1's record re-read (~24 MB).
__global__ __launch_bounds__(256) void spmm1_fused_kernel(
    const int* __restrict__ bstart, const float2* __restrict__ xs,
    const float* __restrict__ W, __hip_bfloat16* __restrict__ h)
{
    __shared__ float2 recs[X_CAP];   // 40 KB
    __shared__ int rcnt[BROWS];
    __shared__ int rofs[BROWS];      // inclusive scan of rcnt
    __shared__ int curs[BROWS];
    const int b = blockIdx.x;
    const int brow0 = b * BROWS;
    const int rows_n = min(BROWS, N_NODES - brow0);
    const int base = bstart[b];
    int size = bstart[b + 1] - base;
    if (size > X_CAP) size = X_CAP;   // LDS guard (mean+24sigma; statistically never)
    const int t = threadIdx.x;

    rcnt[t] = 0;
    __syncthreads();
    for (int i = t; i < size; i += 256)
        atomicAdd(&rcnt[__float_as_uint(xs[base + i].y) & (BROWS - 1)], 1);
    __syncthreads();
    rofs[t] = rcnt[t];
    __syncthreads();
    for (int off = 1; off < 256; off <<= 1) {
        int v = (t >= off) ? rofs[t - off] : 0;
        __syncthreads();
        rofs[t] += v;
        __syncthreads();
    }
    curs[t] = (t > 0) ? rofs[t - 1] : 0;
    __syncthreads();
    for (int i = t; i < size; i += 256) {
        float2 rec = xs[base + i];
        unsigned u = __float_as_uint(rec.y);
        int pos = atomicAdd(&curs[u & (BROWS - 1)], 1);
        recs[pos] = make_float2(rec.x, __int_as_float((int)(u >> 8)));
    }
    __syncthreads();

    const int wv = t >> 6, lane = t & 63;
    for (int rr = 0; rr < 64; ++rr) {
        const int r = wv * 64 + rr;
        if (r >= rows_n) break;
        const int s  = (r > 0) ? rofs[r - 1] : 0;
        const int e2 = rofs[r];
        float acc = 0.0f;
        int j = s;
        for (; j + 4 <= e2; j += 4) {
            float2 p0 = recs[j + 0];
            float2 p1 = recs[j + 1];
            float2 p2 = recs[j + 2];
            float2 p3 = recs[j + 3];
            float g0 = W[__float_as_int(p0.y) * OUT_DIM + lane];
            float g1 = W[__float_as_int(p1.y) * OUT_DIM + lane];
            float g2 = W[__float_as_int(p2.y) * OUT_DIM + lane];
            float g3 = W[__float_as_int(p3.y) * OUT_DIM + lane];
            acc += p0.x * g0;
            acc += p1.x * g1;
            acc += p2.x * g2;
            acc += p3.x * g3;
        }
        for (; j < e2; ++j) {
            float2 p = recs[j];
            acc += p.x * W[__float_as_int(p.y) * OUT_DIM + lane];
        }
        h[(size_t)(brow0 + r) * OUT_DIM + lane] = __float2bfloat16(acc);
    }
}

// ============ reorder_a: in-bucket row-grouping + per-row start (for spmm2) ============
__global__ __launch_bounds__(256) void reorder_a_kernel(
    const int* __restrict__ bstart, float2* __restrict__ data,
    int* __restrict__ start)
{
    __shared__ float2 recs[A_CAP];
    __shared__ int rcnt[BROWS];
    __shared__ int sc[BROWS];
    __shared__ int curs[BROWS];
    const int b = blockIdx.x;
    const int brow0 = b * BROWS;
    const int rows_n = min(BROWS, N_NODES - brow0);
    const int base = bstart[b];
    int size = bstart[b + 1] - base;
    if (size > A_CAP) size = A_CAP;   // LDS guard (statistically never)
    const int t = threadIdx.x;

    rcnt[t] = 0;
    __syncthreads();
    for (int i = t; i < size; i += 256) {
        float2 rec = data[base + i];
        recs[i] = rec;
        atomicAdd(&rcnt[__float_as_uint(rec.y) & (BROWS - 1)], 1);
    }
    __syncthreads();
    sc[t] = rcnt[t];
    __syncthreads();
    for (int off = 1; off < 256; off <<= 1) {
        int v = (t >= off) ? sc[t - off] : 0;
        __syncthreads();
        sc[t] += v;
        __syncthreads();
    }
    int excl = (t > 0) ? sc[t - 1] : 0;
    curs[t] = base + excl;
    if (t < rows_n) start[brow0 + t] = base + excl;
    if (brow0 + rows_n == N_NODES && t == rows_n - 1) start[N_NODES] = base + size;
    __syncthreads();
    for (int i = t; i < size; i += 256) {
        float2 rec = recs[i];
        unsigned u = __float_as_uint(rec.y);
        int pos = atomicAdd(&curs[u & (BROWS - 1)], 1);
        data[pos] = make_float2(rec.x, __int_as_float((int)(u >> 8)));
    }
}

// ============ spmm2 (one wave per row, register accum, 16-deep MLP) ============
__global__ __launch_bounds__(256) void spmm2_csr_kernel(
    const int* __restrict__ as_start, const float2* __restrict__ as,
    const __hip_bfloat16* __restrict__ h, float* __restrict__ out)
{
    const int wave = (int)((blockIdx.x * blockDim.x + threadIdx.x) >> 6);
    const int lane = threadIdx.x & 63;
    if (wave >= N_NODES) return;

    const int s = as_start[wave];
    const int e = as_start[wave + 1];
    float acc = 0.0f;
    int j = s;
    for (; j + 16 <= e; j += 16) {
        float2 q[16];
#pragma unroll
        for (int k = 0; k < 16; ++k) q[k] = as[j + k];
        float g[16];
#pragma unroll
        for (int k = 0; k < 16; ++k)
            g[k] = __bfloat162float(h[(size_t)__float_as_int(q[k].y) * OUT_DIM + lane]);
#pragma unroll
        for (int k = 0; k < 16; ++k) acc += q[k].x * g[k];
    }
    for (; j + 8 <= e; j += 8) {
        float2 q[8];
#pragma unroll
        for (int k = 0; k < 8; ++k) q[k] = as[j + k];
        float g[8];
#pragma unroll
        for (int k = 0; k < 8; ++k)
            g[k] = __bfloat162float(h[(size_t)__float_as_int(q[k].y) * OUT_DIM + lane]);
#pragma unroll
        for (int k = 0; k < 8; ++k) acc += q[k].x * g[k];
    }
    for (; j < e; ++j) {
        float2 p = as[j];
        acc += p.x * __bfloat162float(h[(size_t)__float_as_int(p.y) * OUT_DIM + lane]);
    }
    float r = acc > 0.0f ? acc : 0.0f;
    __builtin_nontemporal_store(r, &out[(size_t)wave * OUT_DIM + lane]);  // never re-read
}

// ======================= fallback (atomic) path =======================

__global__ __launch_bounds__(256) void spmm1_atomic_kernel(
    const float* __restrict__ x_vals, const int* __restrict__ x_rows,
    const int* __restrict__ x_cols, const int* __restrict__ keep,
    const float* __restrict__ W, float* __restrict__ h, int nnz)
{
    const int lane   = threadIdx.x & 63;
    const int group  = (int)((blockIdx.x * blockDim.x + threadIdx.x) >> 6);
    const int stride = (int)((gridDim.x * blockDim.x) >> 6);
    for (int e = group; e < nnz; e += stride) {
        float v = (keep[e] != 0) ? x_vals[e] * INV_KEEP : 0.0f;
        if (v != 0.0f)
            atomicAdd(&h[(size_t)x_rows[e] * OUT_DIM + lane],
                      v * W[x_cols[e] * OUT_DIM + lane]);
    }
}

__global__ __launch_bounds__(256) void spmm2_atomic_kernel(
    const float* __restrict__ adj_vals, const int* __restrict__ adj_rows,
    const int* __restrict__ adj_cols, const float* __restrict__ h,
    float* __restrict__ out, int nnz)
{
    const int lane   = threadIdx.x & 63;
    const int group  = (int)((blockIdx.x * blockDim.x + threadIdx.x) >> 6);
    const int stride = (int)((gridDim.x * blockDim.x) >> 6);
    for (int e = group; e < nnz; e += stride) {
        atomicAdd(&out[(size_t)adj_rows[e] * OUT_DIM + lane],
                  adj_vals[e] * h[(size_t)adj_cols[e] * OUT_DIM + lane]);
    }
}

__global__ __launch_bounds__(256) void relu_kernel(float* __restrict__ out, int n)
{
    int i = (int)(blockIdx.x * blockDim.x + threadIdx.x);
    if (i < n) {
        float v = out[i];
        out[i] = v > 0.0f ? v : 0.0f;
    }
}

// ======================= launch =======================

extern "C" void kernel_launch(void* const* d_in, const int* in_sizes, int n_in,
                              void* d_out, int out_size, void* d_ws, size_t ws_size,
                              hipStream_t stream)
{
    const float* x_vals   = (const float*)d_in[0];
    const int*   x_rows   = (const int*)d_in[1];
    const int*   x_cols   = (const int*)d_in[2];
    const float* adj_vals = (const float*)d_in[3];
    const int*   adj_rows = (const int*)d_in[4];
    const int*   adj_cols = (const int*)d_in[5];
    const float* W        = (const float*)d_in[6];
    const int*   keep     = (const int*)d_in[7];

    const int x_nnz = in_sizes[0];
    const int a_nnz = in_sizes[3];

    float* out = (float*)d_out;

    // workspace layout
    char* ws = (char*)d_ws;
    size_t off = 0;
    float2* xs = (float2*)(ws + off);                 off += (size_t)x_nnz * 8;      // 12.8 MB
    float2* as = (float2*)(ws + off);                 off += (size_t)a_nnz * 8;      // 25.6 MB
    __hip_bfloat16* hb = (__hip_bfloat16*)(ws + off); off += (size_t)N_NODES * OUT_DIM * 2; // 12.8 MB
    int* a_start   = (int*)(ws + off);                off += (size_t)(N_NODES + 1) * 4;
    int* cnt_blk_x = (int*)(ws + off);                off += (size_t)PBLK * NBUCKET * 4;   // 400 KB
    int* cnt_blk_a = (int*)(ws + off);                off += (size_t)PBLK * NBUCKET * 4;   // 400 KB
    int* btot_x    = (int*)(ws + off);                off += (size_t)NBUCKET * 4;
    int* btot_a    = (int*)(ws + off);                off += (size_t)NBUCKET * 4;
    int* bstart_x  = (int*)(ws + off);                off += (size_t)(NBUCKET + 1) * 4;
    int* bstart_a  = (int*)(ws + off);                off += (size_t)(NBUCKET + 1) * 4;
    const size_t needed = off;

    if (ws_size >= needed) {
        // -------- zero-atomic CSR-build + fused/register SpMM --------
        hist_count_kernel<<<2 * PBLK, 256, 0, stream>>>(
            x_rows, keep, adj_rows, cnt_blk_x, cnt_blk_a, x_nnz, a_nnz);

        colscan_kernel<<<2 * NBUCKET, 256, 0, stream>>>(
            cnt_blk_x, cnt_blk_a, btot_x, btot_a);

        bucket_scan_kernel<<<2, 512, 0, stream>>>(
            btot_x, btot_a, bstart_x, bstart_a);

        partition_place_kernel<<<2 * PBLK, 256, 0, stream>>>(
            x_vals, x_rows, x_cols, keep, adj_vals, adj_rows, adj_cols,
            cnt_blk_x, cnt_blk_a, bstart_x, bstart_a, xs, as, x_nnz, a_nnz);

        spmm1_fused_kernel<<<NBUCKET, 256, 0, stream>>>(bstart_x, xs, W, hb);

        reorder_a_kernel<<<NBUCKET, 256, 0, stream>>>(bstart_a, as, a_start);

        const int blocks = (N_NODES * 64 + 255) / 256;  // one wave per row
        spmm2_csr_kernel<<<blocks, 256, 0, stream>>>(a_start, as, hb, out);
    } else {
        // -------- fallback: atomic path --------
        float* hf = (float*)d_ws;
        hipMemsetAsync(hf, 0, (size_t)N_NODES * OUT_DIM * 4, stream);
        hipMemsetAsync(out, 0, (size_t)out_size * 4, stream);
        spmm1_atomic_kernel<<<4096, 256, 0, stream>>>(x_vals, x_rows, x_cols, keep, W, hf, x_nnz);
        spmm2_atomic_kernel<<<4096, 256, 0, stream>>>(adj_vals, adj_rows, adj_cols, hf, out, a_nnz);
        relu_kernel<<<(out_size + 255) / 256, 256, 0, stream>>>(out, out_size);
    }
}

// Round 18
// 301.391 us; speedup vs baseline: 1.0382x; 1.0382x over previous
//
#include <hip/hip_runtime.h>
#include <hip/hip_bf16.h>

#define N_NODES 100000
#define IN_DIM 256
#define OUT_DIM 64
#define INV_KEEP 1.1111111111111112f  // 1/0.9

// bucket = 256 consecutive rows; record = (val, col<<8 | row&255)
#define BROWS 256
#define NBUCKET ((N_NODES + BROWS - 1) / BROWS)   // 391
#define PBLK 256     // chunking blocks per array for hist/place
#define A_CAP 9728   // max records/bucket (mean 8184, sigma 90 -> +17 sigma)
#define X_CAP 5120   // mean ~3680, sigma 60 -> +24 sigma

__device__ __forceinline__ int   ldnt (const int* p)   { return __builtin_nontemporal_load(p); }
__device__ __forceinline__ float ldntf(const float* p) { return __builtin_nontemporal_load(p); }

// ============ pass 1: per-(block,bucket) counts, no global atomics ============
__global__ __launch_bounds__(256) void hist_count_kernel(
    const int* __restrict__ xr, const int* __restrict__ keep,
    const int* __restrict__ ar,
    int* __restrict__ cnt_blk_x, int* __restrict__ cnt_blk_a,
    int x_nnz, int a_nnz)
{
    __shared__ int cnt[NBUCKET];
    const bool isA = blockIdx.x >= PBLK;
    const int ib = isA ? (int)blockIdx.x - PBLK : (int)blockIdx.x;
    const int nnz = isA ? a_nnz : x_nnz;
    const int chunk = (nnz + PBLK - 1) / PBLK;
    const int lo = ib * chunk, hi = min(lo + chunk, nnz);

    for (int k = threadIdx.x; k < NBUCKET; k += 256) cnt[k] = 0;
    __syncthreads();
    if (isA) {
        for (int e = lo + (int)threadIdx.x; e < hi; e += 256)
            atomicAdd(&cnt[ldnt(ar + e) >> 8], 1);
    } else {
        for (int e = lo + (int)threadIdx.x; e < hi; e += 256)
            if (ldnt(keep + e) != 0) atomicAdd(&cnt[ldnt(xr + e) >> 8], 1);
    }
    __syncthreads();
    int* dst = (isA ? cnt_blk_a : cnt_blk_x) + (size_t)ib * NBUCKET;
    for (int k = threadIdx.x; k < NBUCKET; k += 256) dst[k] = cnt[k];
}

// ============ pass 2a: per-bucket exclusive scan over PBLK block counts ============
__global__ __launch_bounds__(256) void colscan_kernel(
    int* __restrict__ cnt_blk_x, int* __restrict__ cnt_blk_a,
    int* __restrict__ btot_x, int* __restrict__ btot_a)
{
    const bool isA = blockIdx.x >= NBUCKET;
    const int k = isA ? (int)blockIdx.x - NBUCKET : (int)blockIdx.x;
    int* cb = isA ? cnt_blk_a : cnt_blk_x;
    __shared__ int sc[PBLK];
    const int t = threadIdx.x;                 // 256 == PBLK
    int v = cb[(size_t)t * NBUCKET + k];
    sc[t] = v;
    __syncthreads();
    for (int off = 1; off < PBLK; off <<= 1) {
        int u = (t >= off) ? sc[t - off] : 0;
        __syncthreads();
        sc[t] += u;
        __syncthreads();
    }
    cb[(size_t)t * NBUCKET + k] = sc[t] - v;   // exclusive within bucket
    if (t == PBLK - 1) (isA ? btot_a : btot_x)[k] = sc[t];
}

// ============ pass 2b: scan bucket totals -> bstart ============
__global__ __launch_bounds__(512) void bucket_scan_kernel(
    const int* __restrict__ btot_x, const int* __restrict__ btot_a,
    int* __restrict__ bstart_x, int* __restrict__ bstart_a)
{
    const int* c = blockIdx.x ? btot_a : btot_x;
    int* bs      = blockIdx.x ? bstart_a : bstart_x;
    __shared__ int sc[512];
    const int t = threadIdx.x;
    sc[t] = (t < NBUCKET) ? c[t] : 0;
    __syncthreads();
    for (int off = 1; off < 512; off <<= 1) {
        int u = (t >= off) ? sc[t - off] : 0;
        __syncthreads();
        sc[t] += u;
        __syncthreads();
    }
    if (t < NBUCKET) bs[t] = (t > 0) ? sc[t - 1] : 0;
    if (t == NBUCKET - 1) bs[NBUCKET] = sc[t];
}

// ============ pass 3: single-pass placement into exact block-private ranges ============
__global__ __launch_bounds__(256) void partition_place_kernel(
    const float* __restrict__ xv, const int* __restrict__ xr,
    const int* __restrict__ xc, const int* __restrict__ keep,
    const float* __restrict__ av, const int* __restrict__ ar,
    const int* __restrict__ ac,
    const int* __restrict__ cnt_blk_x, const int* __restrict__ cnt_blk_a,
    const int* __restrict__ bstart_x, const int* __restrict__ bstart_a,
    float2* __restrict__ xs, float2* __restrict__ as, int x_nnz, int a_nnz)
{
    __shared__ int off_l[NBUCKET];
    const bool isA = blockIdx.x >= PBLK;
    const int ib = isA ? (int)blockIdx.x - PBLK : (int)blockIdx.x;
    const int nnz = isA ? a_nnz : x_nnz;
    const int chunk = (nnz + PBLK - 1) / PBLK;
    const int lo = ib * chunk, hi = min(lo + chunk, nnz);
    const int* cb = (isA ? cnt_blk_a : cnt_blk_x) + (size_t)ib * NBUCKET;
    const int* bs = isA ? bstart_a : bstart_x;
    float2* out   = isA ? as : xs;

    for (int k = threadIdx.x; k < NBUCKET; k += 256) off_l[k] = bs[k] + cb[k];
    __syncthreads();
    if (isA) {
        for (int e = lo + (int)threadIdx.x; e < hi; e += 256) {
            int r = ldnt(ar + e), c = ldnt(ac + e);
            float v = ldntf(av + e);
            int pos = atomicAdd(&off_l[r >> 8], 1);
            out[pos] = make_float2(v, __uint_as_float(((unsigned)c << 8) | (unsigned)(r & (BROWS - 1))));
        }
    } else {
        for (int e = lo + (int)threadIdx.x; e < hi; e += 256) {
            if (ldnt(keep + e) == 0) continue;
            int r = ldnt(xr + e), c = ldnt(xc + e);
            float v = ldntf(xv + e) * INV_KEEP;
            int pos = atomicAdd(&off_l[r >> 8], 1);
            out[pos] = make_float2(v, __uint_as_float(((unsigned)c << 8) | (unsigned)(r & (BROWS - 1))));
        }
    }
}

// ============ reorder: in-bucket row-grouping + per-row start ============
template <int CAP>
__global__ __launch_bounds__(256) void reorder_kernel(
    const int* __restrict__ bstart, float2* __restrict__ data,
    int* __restrict__ start)
{
    __shared__ float2 recs[CAP];
    __shared__ int rcnt[BROWS];
    __shared__ int sc[BROWS];
    __shared__ int curs[BROWS];
    const int b = blockIdx.x;
    const int brow0 = b * BROWS;
    const int rows_n = min(BROWS, N_NODES - brow0);
    const int base = bstart[b];
    int size = bstart[b + 1] - base;
    if (size > CAP) size = CAP;   // LDS-capacity guard (statistically never)
    const int t = threadIdx.x;

    rcnt[t] = 0;
    __syncthreads();
    for (int i = t; i < size; i += 256) {
        float2 rec = data[base + i];
        recs[i] = rec;
        atomicAdd(&rcnt[__float_as_uint(rec.y) & (BROWS - 1)], 1);
    }
    __syncthreads();
    sc[t] = rcnt[t];
    __syncthreads();
    for (int off = 1; off < 256; off <<= 1) {
        int v = (t >= off) ? sc[t - off] : 0;
        __syncthreads();
        sc[t] += v;
        __syncthreads();
    }
    int excl = (t > 0) ? sc[t - 1] : 0;
    curs[t] = base + excl;
    if (t < rows_n) start[brow0 + t] = base + excl;
    if (brow0 + rows_n == N_NODES && t == rows_n - 1) start[N_NODES] = base + size;
    __syncthreads();
    for (int i = t; i < size; i += 256) {
        float2 rec = recs[i];
        unsigned u = __float_as_uint(rec.y);
        int pos = atomicAdd(&curs[u & (BROWS - 1)], 1);
        data[pos] = make_float2(rec.x, __int_as_float((int)(u >> 8)));
    }
}

// ============ SpMM (one wave per row, register accum, MLP-unrolled) ============

__global__ __launch_bounds__(256) void spmm1_csr_kernel(
    const int* __restrict__ xs_start, const float2* __restrict__ xs,
    const float* __restrict__ W, __hip_bfloat16* __restrict__ h)
{
    const int wave = (int)((blockIdx.x * blockDim.x + threadIdx.x) >> 6);
    const int lane = threadIdx.x & 63;
    if (wave >= N_NODES) return;

    const int s = xs_start[wave];
    const int e = xs_start[wave + 1];
    float acc = 0.0f;
    int j = s;
    for (; j + 4 <= e; j += 4) {
        float2 p0 = xs[j + 0];
        float2 p1 = xs[j + 1];
        float2 p2 = xs[j + 2];
        float2 p3 = xs[j + 3];
        float g0 = W[__float_as_int(p0.y) * OUT_DIM + lane];
        float g1 = W[__float_as_int(p1.y) * OUT_DIM + lane];
        float g2 = W[__float_as_int(p2.y) * OUT_DIM + lane];
        float g3 = W[__float_as_int(p3.y) * OUT_DIM + lane];
        acc += p0.x * g0;
        acc += p1.x * g1;
        acc += p2.x * g2;
        acc += p3.x * g3;
    }
    for (; j < e; ++j) {
        float2 p = xs[j];
        acc += p.x * W[__float_as_int(p.y) * OUT_DIM + lane];
    }
    h[(size_t)wave * OUT_DIM + lane] = __float2bfloat16(acc);   // cached: spmm2 reuses
}

__global__ __launch_bounds__(256) void spmm2_csr_kernel(
    const int* __restrict__ as_start, const float2* __restrict__ as,
    const __hip_bfloat16* __restrict__ h, float* __restrict__ out)
{
    const int wave = (int)((blockIdx.x * blockDim.x + threadIdx.x) >> 6);
    const int lane = threadIdx.x & 63;
    if (wave >= N_NODES) return;

    const int s = as_start[wave];
    const int e = as_start[wave + 1];
    float acc = 0.0f;
    int j = s;
    // 16-deep MLP block: issue 16 independent gathers before any use
    for (; j + 16 <= e; j += 16) {
        float2 q[16];
#pragma unroll
        for (int k = 0; k < 16; ++k) q[k] = as[j + k];
        float g[16];
#pragma unroll
        for (int k = 0; k < 16; ++k)
            g[k] = __bfloat162float(h[(size_t)__float_as_int(q[k].y) * OUT_DIM + lane]);
#pragma unroll
        for (int k = 0; k < 16; ++k) acc += q[k].x * g[k];
    }
    for (; j + 8 <= e; j += 8) {
        float2 q[8];
#pragma unroll
        for (int k = 0; k < 8; ++k) q[k] = as[j + k];
        float g[8];
#pragma unroll
        for (int k = 0; k < 8; ++k)
            g[k] = __bfloat162float(h[(size_t)__float_as_int(q[k].y) * OUT_DIM + lane]);
#pragma unroll
        for (int k = 0; k < 8; ++k) acc += q[k].x * g[k];
    }
    for (; j < e; ++j) {
        float2 p = as[j];
        acc += p.x * __bfloat162float(h[(size_t)__float_as_int(p.y) * OUT_DIM + lane]);
    }
    float r = acc > 0.0f ? acc : 0.0f;
    __builtin_nontemporal_store(r, &out[(size_t)wave * OUT_DIM + lane]);  // never re-read
}

// ======================= fallback (atomic) path =======================

__global__ __launch_bounds__(256) void spmm1_atomic_kernel(
    const float* __restrict__ x_vals, const int* __restrict__ x_rows,
    const int* __restrict__ x_cols, const int* __restrict__ keep,
    const float* __restrict__ W, float* __restrict__ h, int nnz)
{
    const int lane   = threadIdx.x & 63;
    const int group  = (int)((blockIdx.x * blockDim.x + threadIdx.x) >> 6);
    const int stride = (int)((gridDim.x * blockDim.x) >> 6);
    for (int e = group; e < nnz; e += stride) {
        float v = (keep[e] != 0) ? x_vals[e] * INV_KEEP : 0.0f;
        if (v != 0.0f)
            atomicAdd(&h[(size_t)x_rows[e] * OUT_DIM + lane],
                      v * W[x_cols[e] * OUT_DIM + lane]);
    }
}

__global__ __launch_bounds__(256) void spmm2_atomic_kernel(
    const float* __restrict__ adj_vals, const int* __restrict__ adj_rows,
    const int* __restrict__ adj_cols, const float* __restrict__ h,
    float* __restrict__ out, int nnz)
{
    const int lane   = threadIdx.x & 63;
    const int group  = (int)((blockIdx.x * blockDim.x + threadIdx.x) >> 6);
    const int stride = (int)((gridDim.x * blockDim.x) >> 6);
    for (int e = group; e < nnz; e += stride) {
        atomicAdd(&out[(size_t)adj_rows[e] * OUT_DIM + lane],
                  adj_vals[e] * h[(size_t)adj_cols[e] * OUT_DIM + lane]);
    }
}

__global__ __launch_bounds__(256) void relu_kernel(float* __restrict__ out, int n)
{
    int i = (int)(blockIdx.x * blockDim.x + threadIdx.x);
    if (i < n) {
        float v = out[i];
        out[i] = v > 0.0f ? v : 0.0f;
    }
}

// ======================= launch =======================

extern "C" void kernel_launch(void* const* d_in, const int* in_sizes, int n_in,
                              void* d_out, int out_size, void* d_ws, size_t ws_size,
                              hipStream_t stream)
{
    const float* x_vals   = (const float*)d_in[0];
    const int*   x_rows   = (const int*)d_in[1];
    const int*   x_cols   = (const int*)d_in[2];
    const float* adj_vals = (const float*)d_in[3];
    const int*   adj_rows = (const int*)d_in[4];
    const int*   adj_cols = (const int*)d_in[5];
    const float* W        = (const float*)d_in[6];
    const int*   keep     = (const int*)d_in[7];

    const int x_nnz = in_sizes[0];
    const int a_nnz = in_sizes[3];

    float* out = (float*)d_out;

    // workspace layout
    char* ws = (char*)d_ws;
    size_t off = 0;
    float2* xs = (float2*)(ws + off);                 off += (size_t)x_nnz * 8;      // 12.8 MB
    float2* as = (float2*)(ws + off);                 off += (size_t)a_nnz * 8;      // 25.6 MB
    __hip_bfloat16* hb = (__hip_bfloat16*)(ws + off); off += (size_t)N_NODES * OUT_DIM * 2; // 12.8 MB
    int* x_start   = (int*)(ws + off);                off += (size_t)(N_NODES + 1) * 4;
    int* a_start   = (int*)(ws + off);                off += (size_t)(N_NODES + 1) * 4;
    int* cnt_blk_x = (int*)(ws + off);                off += (size_t)PBLK * NBUCKET * 4;   // 400 KB
    int* cnt_blk_a = (int*)(ws + off);                off += (size_t)PBLK * NBUCKET * 4;   // 400 KB
    int* btot_x    = (int*)(ws + off);                off += (size_t)NBUCKET * 4;
    int* btot_a    = (int*)(ws + off);                off += (size_t)NBUCKET * 4;
    int* bstart_x  = (int*)(ws + off);                off += (size_t)(NBUCKET + 1) * 4;
    int* bstart_a  = (int*)(ws + off);                off += (size_t)(NBUCKET + 1) * 4;
    const size_t needed = off;

    if (ws_size >= needed) {
        // -------- zero-atomic CSR-build + register SpMM --------
        hist_count_kernel<<<2 * PBLK, 256, 0, stream>>>(
            x_rows, keep, adj_rows, cnt_blk_x, cnt_blk_a, x_nnz, a_nnz);

        colscan_kernel<<<2 * NBUCKET, 256, 0, stream>>>(
            cnt_blk_x, cnt_blk_a, btot_x, btot_a);

        bucket_scan_kernel<<<2, 512, 0, stream>>>(
            btot_x, btot_a, bstart_x, bstart_a);

        partition_place_kernel<<<2 * PBLK, 256, 0, stream>>>(
            x_vals, x_rows, x_cols, keep, adj_vals, adj_rows, adj_cols,
            cnt_blk_x, cnt_blk_a, bstart_x, bstart_a, xs, as, x_nnz, a_nnz);

        reorder_kernel<X_CAP><<<NBUCKET, 256, 0, stream>>>(bstart_x, xs, x_start);
        reorder_kernel<A_CAP><<<NBUCKET, 256, 0, stream>>>(bstart_a, as, a_start);

        const int blocks = (N_NODES * 64 + 255) / 256;  // one wave per row
        spmm1_csr_kernel<<<blocks, 256, 0, stream>>>(x_start, xs, W, hb);
        spmm2_csr_kernel<<<blocks, 256, 0, stream>>>(a_start, as, hb, out);
    } else {
        // -------- fallback: atomic path --------
        float* hf = (float*)d_ws;
        hipMemsetAsync(hf, 0, (size_t)N_NODES * OUT_DIM * 4, stream);
        hipMemsetAsync(out, 0, (size_t)out_size * 4, stream);
        spmm1_atomic_kernel<<<4096, 256, 0, stream>>>(x_vals, x_rows, x_cols, keep, W, hf, x_nnz);
        spmm2_atomic_kernel<<<4096, 256, 0, stream>>>(adj_vals, adj_rows, adj_cols, hf, out, a_nnz);
        relu_kernel<<<(out_size + 255) / 256, 256, 0, stream>>>(out, out_size);
    }
}